// Round 1
// baseline (512.031 us; speedup 1.0000x reference)
//
#include <hip/hip_runtime.h>
#include <math.h>

constexpr int B = 16, F = 64, E = 16, H = 64, W = 64;
constexpr int HW = H * W;

// ---------------------------------------------------------------------------
// conv1: 3x3 same conv, 64->64 ch, + bias, relu.  block = one (b,y) row.
// thread owns 4 o x 4 x outputs; input rows staged in LDS (52 KB).
// ---------------------------------------------------------------------------
__global__ __launch_bounds__(256) void conv1_kernel(
    const float* __restrict__ in, const float* __restrict__ wgt,
    const float* __restrict__ bias, float* __restrict__ out)
{
    __shared__ __align__(16) float s_in[3][F][68];
    const int b = blockIdx.y, y = blockIdx.x;
    const int tid = threadIdx.x;

    for (int i = tid; i < 3 * F * W; i += 256) {
        int r = i / (F * W);
        int rem = i - r * F * W;
        int c = rem >> 6;
        int x = rem & 63;
        int yy = y + r - 1;
        float v = 0.f;
        if (yy >= 0 && yy < H) v = in[((b * F + c) * H + yy) * W + x];
        s_in[r][c][x + 1] = v;
    }
    for (int i = tid; i < 3 * F; i += 256) {
        int r = i / F, c = i - r * F;
        s_in[r][c][0] = 0.f;
        s_in[r][c][W + 1] = 0.f;
        s_in[r][c][W + 2] = 0.f;
        s_in[r][c][W + 3] = 0.f;
    }
    __syncthreads();

    const int og = tid >> 4;           // 0..15 -> o = og*4 .. +3
    const int x0 = (tid & 15) * 4;     // 4 consecutive x
    float acc[4][4] = {};

    for (int c = 0; c < F; ++c) {
        float wr[4][9];
        #pragma unroll
        for (int i = 0; i < 4; ++i) {
            const float* wp = wgt + ((og * 4 + i) * F + c) * 9;
            #pragma unroll
            for (int t = 0; t < 9; ++t) wr[i][t] = wp[t];
        }
        #pragma unroll
        for (int dy = 0; dy < 3; ++dy) {
            float4 p0 = *(const float4*)&s_in[dy][c][x0];
            float4 p1 = *(const float4*)&s_in[dy][c][x0 + 4];
            float v[8] = {p0.x, p0.y, p0.z, p0.w, p1.x, p1.y, p1.z, p1.w};
            #pragma unroll
            for (int i = 0; i < 4; ++i)
                #pragma unroll
                for (int dx = 0; dx < 3; ++dx)
                    #pragma unroll
                    for (int j = 0; j < 4; ++j)
                        acc[i][j] = fmaf(wr[i][dy * 3 + dx], v[j + dx], acc[i][j]);
        }
    }

    #pragma unroll
    for (int i = 0; i < 4; ++i) {
        int o = og * 4 + i;
        float bo = bias[o];
        #pragma unroll
        for (int j = 0; j < 4; ++j)
            out[((b * F + o) * H + y) * W + x0 + j] = fmaxf(acc[i][j] + bo, 0.f);
    }
}

// ---------------------------------------------------------------------------
// conv2: 3x3 same conv, 64->16 ch, + bias, sigmoid -> attn (B,E,H,W).
// block covers 4 rows; input staged per 32-channel chunk (52 KB LDS).
// thread owns 4 e x 4 x at one row.
// ---------------------------------------------------------------------------
__global__ __launch_bounds__(256) void conv2_kernel(
    const float* __restrict__ in, const float* __restrict__ wgt,
    const float* __restrict__ bias, float* __restrict__ attn)
{
    __shared__ __align__(16) float s_in[6][32][68];
    const int b = blockIdx.y;
    const int y0 = blockIdx.x * 4;
    const int tid = threadIdx.x;
    const int yloc = tid >> 6;          // 0..3
    const int rem = tid & 63;
    const int eg = rem >> 4;            // 0..3 -> e = eg*4 .. +3
    const int x0 = (rem & 15) * 4;
    const int y = y0 + yloc;
    float acc[4][4] = {};

    for (int cc = 0; cc < F; cc += 32) {
        __syncthreads();
        for (int i = tid; i < 6 * 32 * W; i += 256) {
            int r = i >> 11;            // /(32*64)
            int rem2 = i & 2047;
            int c = rem2 >> 6;
            int x = rem2 & 63;
            int yy = y0 + r - 1;
            float v = 0.f;
            if (yy >= 0 && yy < H) v = in[((b * F + cc + c) * H + yy) * W + x];
            s_in[r][c][x + 1] = v;
        }
        for (int i = tid; i < 6 * 32; i += 256) {
            int r = i >> 5, c = i & 31;
            s_in[r][c][0] = 0.f;
            s_in[r][c][W + 1] = 0.f;
            s_in[r][c][W + 2] = 0.f;
            s_in[r][c][W + 3] = 0.f;
        }
        __syncthreads();

        for (int c = 0; c < 32; ++c) {
            float wr[4][9];
            #pragma unroll
            for (int i = 0; i < 4; ++i) {
                const float* wp = wgt + ((eg * 4 + i) * F + cc + c) * 9;
                #pragma unroll
                for (int t = 0; t < 9; ++t) wr[i][t] = wp[t];
            }
            #pragma unroll
            for (int dy = 0; dy < 3; ++dy) {
                float4 p0 = *(const float4*)&s_in[yloc + dy][c][x0];
                float4 p1 = *(const float4*)&s_in[yloc + dy][c][x0 + 4];
                float v[8] = {p0.x, p0.y, p0.z, p0.w, p1.x, p1.y, p1.z, p1.w};
                #pragma unroll
                for (int i = 0; i < 4; ++i)
                    #pragma unroll
                    for (int dx = 0; dx < 3; ++dx)
                        #pragma unroll
                        for (int j = 0; j < 4; ++j)
                            acc[i][j] = fmaf(wr[i][dy * 3 + dx], v[j + dx], acc[i][j]);
            }
        }
    }

    #pragma unroll
    for (int i = 0; i < 4; ++i) {
        int e = eg * 4 + i;
        float be = bias[e];
        #pragma unroll
        for (int j = 0; j < 4; ++j) {
            float r = acc[i][j] + be;
            attn[((b * E + e) * H + y) * W + x0 + j] = 1.f / (1.f + __expf(-r));
        }
    }
}

// ---------------------------------------------------------------------------
// sproj[b,o,y,x] = sum_f c3_w[o,f] * state[b,f,y,x]   (pointwise 64x64 proj)
// ---------------------------------------------------------------------------
__global__ __launch_bounds__(256) void sproj_kernel(
    const float* __restrict__ state, const float* __restrict__ w,
    float* __restrict__ out)
{
    const int b = blockIdx.y, y = blockIdx.x;
    const int tid = threadIdx.x;
    const int og = tid >> 4;
    const int x0 = (tid & 15) * 4;
    float acc[4][4] = {};
    const float* sp = state + (b * F * H + y) * W + x0;

    for (int f = 0; f < F; ++f) {
        float4 v4 = *(const float4*)(sp + f * HW);
        float v[4] = {v4.x, v4.y, v4.z, v4.w};
        #pragma unroll
        for (int i = 0; i < 4; ++i) {
            float wv = w[(og * 4 + i) * F + f];
            #pragma unroll
            for (int j = 0; j < 4; ++j)
                acc[i][j] = fmaf(wv, v[j], acc[i][j]);
        }
    }
    #pragma unroll
    for (int i = 0; i < 4; ++i) {
        int o = og * 4 + i;
        #pragma unroll
        for (int j = 0; j < 4; ++j)
            out[((b * F + o) * H + y) * W + x0 + j] = acc[i][j];
    }
}

// ---------------------------------------------------------------------------
// out[b,e,o] = ( 260*relu(c3_b[o])
//              + sum_{y,x} relu(attn[b,e,y,x]*sproj[b,o,y,x] + c3_b[o]) ) / 4356
// block = one (b,e); attn plane staged in LDS; acc[64] per thread over pixels.
// ---------------------------------------------------------------------------
__global__ __launch_bounds__(256) void reduce_kernel(
    const float* __restrict__ sproj, const float* __restrict__ attn,
    const float* __restrict__ c3_b, float* __restrict__ out)
{
    __shared__ float s_attn[HW];
    __shared__ float s_acc[F];
    const int b = blockIdx.y, e = blockIdx.x;
    const int tid = threadIdx.x;

    const float* ap = attn + (b * E + e) * HW;
    for (int i = tid; i < HW; i += 256) s_attn[i] = ap[i];
    if (tid < F) s_acc[tid] = 0.f;
    __syncthreads();

    float acc[F];
    #pragma unroll
    for (int o = 0; o < F; ++o) acc[o] = 0.f;

    const float* spb = sproj + b * F * HW;
    for (int k = 0; k < HW / 256; ++k) {
        int p = k * 256 + tid;
        float a = s_attn[p];
        #pragma unroll
        for (int o = 0; o < F; ++o) {
            float r = fmaf(a, spb[o * HW + p], c3_b[o]);
            acc[o] += fmaxf(r, 0.f);
        }
    }

    const int lane = tid & 63;
    #pragma unroll
    for (int o = 0; o < F; ++o) {
        float v = acc[o];
        v += __shfl_down(v, 32);
        v += __shfl_down(v, 16);
        v += __shfl_down(v, 8);
        v += __shfl_down(v, 4);
        v += __shfl_down(v, 2);
        v += __shfl_down(v, 1);
        if (lane == 0) atomicAdd(&s_acc[o], v);
    }
    __syncthreads();

    if (tid < F) {
        float border = 260.f * fmaxf(c3_b[tid], 0.f);
        out[(b * E + e) * F + tid] = (s_acc[tid] + border) * (1.f / 4356.f);
    }
}

// ---------------------------------------------------------------------------
extern "C" void kernel_launch(void* const* d_in, const int* in_sizes, int n_in,
                              void* d_out, int out_size, void* d_ws, size_t ws_size,
                              hipStream_t stream) {
    (void)in_sizes; (void)n_in; (void)out_size; (void)ws_size;
    const float* state  = (const float*)d_in[0];
    const float* pre_w  = (const float*)d_in[1];
    const float* pre_b  = (const float*)d_in[2];
    const float* attn_w = (const float*)d_in[3];
    const float* attn_b = (const float*)d_in[4];
    const float* c3_w   = (const float*)d_in[5];
    const float* c3_b   = (const float*)d_in[6];

    float* out      = (float*)d_out;
    float* attn_out = out + B * E * F;          // second output, (B,E,H,W)
    float* xbuf     = (float*)d_ws;             // conv1 output (B,F,H,W)
    float* sproj    = xbuf;                     // reused after conv2 consumed xbuf

    conv1_kernel<<<dim3(H, B), 256, 0, stream>>>(state, pre_w, pre_b, xbuf);
    conv2_kernel<<<dim3(H / 4, B), 256, 0, stream>>>(xbuf, attn_w, attn_b, attn_out);
    sproj_kernel<<<dim3(H, B), 256, 0, stream>>>(state, c3_w, sproj);
    reduce_kernel<<<dim3(E, B), 256, 0, stream>>>(sproj, attn_out, c3_b, out);
}

// Round 2
// 284.098 us; speedup vs baseline: 1.8023x; 1.8023x over previous
//
#include <hip/hip_runtime.h>
#include <math.h>

constexpr int B = 16, F = 64, E = 16, H = 64, W = 64;
constexpr int HW = H * W;

// ---------------------------------------------------------------------------
// repack weights to c-major so conv threads load contiguous float4s.
// wT1[c][o][t] (64*64*9)   wT2[c][e][t] (64*16*9)   wT3[f][o] (64*64)
// ---------------------------------------------------------------------------
__global__ __launch_bounds__(256) void repack_kernel(
    const float* __restrict__ pre_w, const float* __restrict__ attn_w,
    const float* __restrict__ c3_w,
    float* __restrict__ wT1, float* __restrict__ wT2, float* __restrict__ wT3)
{
    int tid = blockIdx.x * 256 + threadIdx.x;
    if (tid < 64 * 64 * 9) {
        int c = tid / 576, r = tid - c * 576, o = r / 9, t = r - o * 9;
        wT1[tid] = pre_w[(o * 64 + c) * 9 + t];
    }
    if (tid < 64 * 16 * 9) {
        int c = tid / 144, r = tid - c * 144, e = r / 9, t = r - e * 9;
        wT2[tid] = attn_w[(e * 64 + c) * 9 + t];
    }
    if (tid < 64 * 64) {
        int f = tid >> 6, o = tid & 63;
        wT3[tid] = c3_w[o * 64 + f];
    }
}

// ---------------------------------------------------------------------------
// conv1: 3x3 same conv, 64->64 ch, + bias, relu.  block = one (b,y) row.
// thread owns 4 o x 4 x outputs; input rows staged in LDS (52 KB).
// weights from repacked wT1 via float4 (16B-aligned: (c*64+og*4)*9*4B).
// ---------------------------------------------------------------------------
__global__ __launch_bounds__(256) void conv1_kernel(
    const float* __restrict__ in, const float* __restrict__ wT1,
    const float* __restrict__ bias, float* __restrict__ out)
{
    __shared__ __align__(16) float s_in[3][F][68];
    const int b = blockIdx.y, y = blockIdx.x;
    const int tid = threadIdx.x;

    for (int i = tid; i < 3 * F * W; i += 256) {
        int r = i / (F * W);
        int rem = i - r * F * W;
        int c = rem >> 6;
        int x = rem & 63;
        int yy = y + r - 1;
        float v = 0.f;
        if (yy >= 0 && yy < H) v = in[((b * F + c) * H + yy) * W + x];
        s_in[r][c][x + 1] = v;
    }
    for (int i = tid; i < 3 * F; i += 256) {
        int r = i / F, c = i - r * F;
        s_in[r][c][0] = 0.f;
        s_in[r][c][W + 1] = 0.f;
        s_in[r][c][W + 2] = 0.f;
        s_in[r][c][W + 3] = 0.f;
    }
    __syncthreads();

    const int og = tid >> 4;           // 0..15 -> o = og*4 .. +3
    const int x0 = (tid & 15) * 4;     // 4 consecutive x
    float acc[4][4] = {};

    for (int c = 0; c < F; ++c) {
        // 36 contiguous weights: [i(4)][tap(9)], 16B aligned
        const float4* wp = (const float4*)(wT1 + (c * 64 + og * 4) * 9);
        float wrf[36];
        #pragma unroll
        for (int t = 0; t < 9; ++t) {
            float4 q = wp[t];
            wrf[4 * t + 0] = q.x; wrf[4 * t + 1] = q.y;
            wrf[4 * t + 2] = q.z; wrf[4 * t + 3] = q.w;
        }
        #pragma unroll
        for (int dy = 0; dy < 3; ++dy) {
            float4 p0 = *(const float4*)&s_in[dy][c][x0];
            float4 p1 = *(const float4*)&s_in[dy][c][x0 + 4];
            float v[8] = {p0.x, p0.y, p0.z, p0.w, p1.x, p1.y, p1.z, p1.w};
            #pragma unroll
            for (int i = 0; i < 4; ++i)
                #pragma unroll
                for (int dx = 0; dx < 3; ++dx)
                    #pragma unroll
                    for (int j = 0; j < 4; ++j)
                        acc[i][j] = fmaf(wrf[i * 9 + dy * 3 + dx], v[j + dx], acc[i][j]);
        }
    }

    #pragma unroll
    for (int i = 0; i < 4; ++i) {
        int o = og * 4 + i;
        float bo = bias[o];
        #pragma unroll
        for (int j = 0; j < 4; ++j)
            out[((b * F + o) * H + y) * W + x0 + j] = fmaxf(acc[i][j] + bo, 0.f);
    }
}

// ---------------------------------------------------------------------------
// conv2: 3x3 same conv, 64->16 ch, + bias, sigmoid -> attn (B,E,H,W).
// block covers 4 rows; input staged per 32-channel chunk (52 KB LDS).
// ---------------------------------------------------------------------------
__global__ __launch_bounds__(256) void conv2_kernel(
    const float* __restrict__ in, const float* __restrict__ wT2,
    const float* __restrict__ bias, float* __restrict__ attn)
{
    __shared__ __align__(16) float s_in[6][32][68];
    const int b = blockIdx.y;
    const int y0 = blockIdx.x * 4;
    const int tid = threadIdx.x;
    const int yloc = tid >> 6;          // 0..3
    const int rem = tid & 63;
    const int eg = rem >> 4;            // 0..3 -> e = eg*4 .. +3
    const int x0 = (rem & 15) * 4;
    const int y = y0 + yloc;
    float acc[4][4] = {};

    for (int cc = 0; cc < F; cc += 32) {
        __syncthreads();
        for (int i = tid; i < 6 * 32 * W; i += 256) {
            int r = i >> 11;
            int rem2 = i & 2047;
            int c = rem2 >> 6;
            int x = rem2 & 63;
            int yy = y0 + r - 1;
            float v = 0.f;
            if (yy >= 0 && yy < H) v = in[((b * F + cc + c) * H + yy) * W + x];
            s_in[r][c][x + 1] = v;
        }
        for (int i = tid; i < 6 * 32; i += 256) {
            int r = i >> 5, c = i & 31;
            s_in[r][c][0] = 0.f;
            s_in[r][c][W + 1] = 0.f;
            s_in[r][c][W + 2] = 0.f;
            s_in[r][c][W + 3] = 0.f;
        }
        __syncthreads();

        for (int c = 0; c < 32; ++c) {
            const float4* wp = (const float4*)(wT2 + ((cc + c) * 16 + eg * 4) * 9);
            float wrf[36];
            #pragma unroll
            for (int t = 0; t < 9; ++t) {
                float4 q = wp[t];
                wrf[4 * t + 0] = q.x; wrf[4 * t + 1] = q.y;
                wrf[4 * t + 2] = q.z; wrf[4 * t + 3] = q.w;
            }
            #pragma unroll
            for (int dy = 0; dy < 3; ++dy) {
                float4 p0 = *(const float4*)&s_in[yloc + dy][c][x0];
                float4 p1 = *(const float4*)&s_in[yloc + dy][c][x0 + 4];
                float v[8] = {p0.x, p0.y, p0.z, p0.w, p1.x, p1.y, p1.z, p1.w};
                #pragma unroll
                for (int i = 0; i < 4; ++i)
                    #pragma unroll
                    for (int dx = 0; dx < 3; ++dx)
                        #pragma unroll
                        for (int j = 0; j < 4; ++j)
                            acc[i][j] = fmaf(wrf[i * 9 + dy * 3 + dx], v[j + dx], acc[i][j]);
            }
        }
    }

    #pragma unroll
    for (int i = 0; i < 4; ++i) {
        int e = eg * 4 + i;
        float be = bias[e];
        #pragma unroll
        for (int j = 0; j < 4; ++j) {
            float r = acc[i][j] + be;
            attn[((b * E + e) * H + y) * W + x0 + j] = 1.f / (1.f + __expf(-r));
        }
    }
}

// ---------------------------------------------------------------------------
// sproj[b,o,y,x] = sum_f wT3[f][o] * state[b,f,y,x]
// ---------------------------------------------------------------------------
__global__ __launch_bounds__(256) void sproj_kernel(
    const float* __restrict__ state, const float* __restrict__ wT3,
    float* __restrict__ out)
{
    const int b = blockIdx.y, y = blockIdx.x;
    const int tid = threadIdx.x;
    const int og = tid >> 4;
    const int x0 = (tid & 15) * 4;
    float acc[4][4] = {};
    const float* sp = state + (b * F * H + y) * W + x0;

    for (int f = 0; f < F; ++f) {
        float4 v4 = *(const float4*)(sp + f * HW);
        float4 wv = ((const float4*)(wT3 + f * 64))[og];
        float v[4] = {v4.x, v4.y, v4.z, v4.w};
        float wvv[4] = {wv.x, wv.y, wv.z, wv.w};
        #pragma unroll
        for (int i = 0; i < 4; ++i)
            #pragma unroll
            for (int j = 0; j < 4; ++j)
                acc[i][j] = fmaf(wvv[i], v[j], acc[i][j]);
    }
    #pragma unroll
    for (int i = 0; i < 4; ++i) {
        int o = og * 4 + i;
        #pragma unroll
        for (int j = 0; j < 4; ++j)
            out[((b * F + o) * H + y) * W + x0 + j] = acc[i][j];
    }
}

// ---------------------------------------------------------------------------
// reduce: out[b,e,o] += sum_p relu(attn[b,e,p]*sproj[b,o,p] + c3_b[o]) / 4356
// grid = (64 pixel chunks of 64, B).  LDS: attn (p-major) + sproj chunk.
// thread: 4e x 4o register tile over 16 pixels; LDS partial-reduce; atomicAdd.
// ---------------------------------------------------------------------------
__global__ __launch_bounds__(256) void reduce_kernel(
    const float* __restrict__ sproj, const float* __restrict__ attn,
    const float* __restrict__ c3_b, float* __restrict__ out)
{
    __shared__ __align__(16) float s_attn[64][16];   // [p][e]
    __shared__ __align__(16) float s_sp[64][64];     // [p][o]; reused for partials
    const int b = blockIdx.y;
    const int chunk = blockIdx.x;
    const int p0 = chunk * 64;
    const int tid = threadIdx.x;

    // stage attn: 16e x 64p, transposed to [p][e]
    {
        int e = tid >> 4, pq = (tid & 15) * 4;
        float4 v = *(const float4*)(attn + (b * E + e) * HW + p0 + pq);
        s_attn[pq + 0][e] = v.x; s_attn[pq + 1][e] = v.y;
        s_attn[pq + 2][e] = v.z; s_attn[pq + 3][e] = v.w;
    }
    // stage sproj: 64o x 64p, transposed to [p][o]
    #pragma unroll
    for (int r = 0; r < 4; ++r) {
        int idx = r * 256 + tid;
        int o = idx >> 4, pq = (idx & 15) * 4;
        float4 v = *(const float4*)(sproj + (b * F + o) * HW + p0 + pq);
        s_sp[pq + 0][o] = v.x; s_sp[pq + 1][o] = v.y;
        s_sp[pq + 2][o] = v.z; s_sp[pq + 3][o] = v.w;
    }
    __syncthreads();

    const int combo = tid & 63;
    const int eg = combo >> 4;       // 0..3
    const int og = combo & 15;       // 0..15
    const int psub = tid >> 6;       // 0..3
    float4 cb4 = ((const float4*)c3_b)[og];
    float cb[4] = {cb4.x, cb4.y, cb4.z, cb4.w};

    float acc[4][4] = {};
    #pragma unroll 2
    for (int pp = 0; pp < 16; ++pp) {
        int p = psub * 16 + pp;
        float4 a4 = *(const float4*)&s_attn[p][eg * 4];
        float4 s4 = *(const float4*)&s_sp[p][og * 4];
        float a[4] = {a4.x, a4.y, a4.z, a4.w};
        float s[4] = {s4.x, s4.y, s4.z, s4.w};
        #pragma unroll
        for (int i = 0; i < 4; ++i)
            #pragma unroll
            for (int j = 0; j < 4; ++j)
                acc[i][j] += fmaxf(fmaf(a[i], s[j], cb[j]), 0.f);
    }

    __syncthreads();
    // write partials into s_sp region: [psub][combo][16]
    float* s_part = &s_sp[0][0];
    #pragma unroll
    for (int i = 0; i < 4; ++i)
        #pragma unroll
        for (int j = 0; j < 4; ++j)
            s_part[(psub * 64 + combo) * 16 + i * 4 + j] = acc[i][j];
    __syncthreads();

    // final: thread handles combo=tid>>2, i=tid&3, j=0..3
    {
        int cmb = tid >> 2, i = tid & 3;
        int e = (cmb >> 4) * 4 + i;
        #pragma unroll
        for (int j = 0; j < 4; ++j) {
            int o = (cmb & 15) * 4 + j;
            float v = 0.f;
            #pragma unroll
            for (int ps = 0; ps < 4; ++ps)
                v += s_part[(ps * 64 + cmb) * 16 + i * 4 + j];
            float add = v * (1.f / 4356.f);
            if (chunk == 0)
                add += 260.f * fmaxf(c3_b[o], 0.f) * (1.f / 4356.f);
            atomicAdd(&out[(b * E + e) * F + o], add);
        }
    }
}

// ---------------------------------------------------------------------------
extern "C" void kernel_launch(void* const* d_in, const int* in_sizes, int n_in,
                              void* d_out, int out_size, void* d_ws, size_t ws_size,
                              hipStream_t stream) {
    (void)in_sizes; (void)n_in; (void)out_size; (void)ws_size;
    const float* state  = (const float*)d_in[0];
    const float* pre_w  = (const float*)d_in[1];
    const float* pre_b  = (const float*)d_in[2];
    const float* attn_w = (const float*)d_in[3];
    const float* attn_b = (const float*)d_in[4];
    const float* c3_w   = (const float*)d_in[5];
    const float* c3_b   = (const float*)d_in[6];

    float* out      = (float*)d_out;
    float* attn_out = out + B * E * F;            // second output (B,E,H,W)

    float* xbuf  = (float*)d_ws;                  // conv1 out / later sproj (16 MB)
    float* wT1   = xbuf + B * F * HW;             // 36864 floats
    float* wT2   = wT1 + 64 * 64 * 9;             // 9216 floats
    float* wT3   = wT2 + 64 * 16 * 9;             // 4096 floats
    float* sproj = xbuf;                          // reuse after conv2 consumed xbuf

    hipMemsetAsync(out, 0, B * E * F * sizeof(float), stream);
    repack_kernel<<<144, 256, 0, stream>>>(pre_w, attn_w, c3_w, wT1, wT2, wT3);
    conv1_kernel<<<dim3(H, B), 256, 0, stream>>>(state, wT1, pre_b, xbuf);
    conv2_kernel<<<dim3(H / 4, B), 256, 0, stream>>>(xbuf, wT2, attn_b, attn_out);
    sproj_kernel<<<dim3(H, B), 256, 0, stream>>>(state, wT3, sproj);
    reduce_kernel<<<dim3(64, B), 256, 0, stream>>>(sproj, attn_out, c3_b, out);
}

// Round 3
// 150.965 us; speedup vs baseline: 3.3917x; 1.8819x over previous
//
#include <hip/hip_runtime.h>
#include <math.h>

constexpr int B = 16, F = 64, E = 16, H = 64, W = 64;
constexpr int HW = H * W;
constexpr int XP = 66;          // padded x dim (1 zero col each side)
constexpr int CP = 72;          // LDS c-dim pad (2-way bank aliasing only)
constexpr int YSTRIDE = XP * F; // 4224 elems per (b,y) row in transposed bufs

typedef __bf16 bf16x8 __attribute__((ext_vector_type(8)));
typedef __bf16 bf16x4 __attribute__((ext_vector_type(4)));
typedef float f32x16 __attribute__((ext_vector_type(16)));
typedef float f32x4 __attribute__((ext_vector_type(4)));

// ---------------------------------------------------------------------------
// transpose state (b,c,y,x) fp32 -> xTs[b][y][x+1][c] bf16, x-borders zeroed.
// ---------------------------------------------------------------------------
__global__ __launch_bounds__(256) void transpose_kernel(
    const float* __restrict__ in, __bf16* __restrict__ xTs)
{
    __shared__ float s_t[64][68];
    const int b = blockIdx.y, y = blockIdx.x;
    const int tid = threadIdx.x;
    {
        int c = tid >> 2, x0 = (tid & 3) * 16;
        const float* src = in + ((size_t)(b * F + c) * H + y) * W + x0;
        #pragma unroll
        for (int q = 0; q < 4; ++q)
            *(float4*)&s_t[c][x0 + 4 * q] = *(const float4*)(src + 4 * q);
    }
    __syncthreads();
    __bf16* dst = xTs + (size_t)(b * H + y) * YSTRIDE;
    #pragma unroll
    for (int i = 0; i < 2; ++i) {
        int t = tid + i * 256;
        int x = t >> 3, cg = t & 7;
        bf16x8 v;
        #pragma unroll
        for (int j = 0; j < 8; ++j) v[j] = (__bf16)s_t[cg * 8 + j][x];
        *(bf16x8*)(dst + (x + 1) * F + cg * 8) = v;
    }
    if (tid < 16) {
        int bd = tid >> 3, cg = tid & 7;
        bf16x8 z = {};
        *(bf16x8*)(dst + (bd ? 65 : 0) * F + cg * 8) = z;
    }
}

// ---------------------------------------------------------------------------
// repack weights: wA1[o][t*64+c] bf16, wA2[e][t*64+c] bf16, wT3[f][o] fp32
// ---------------------------------------------------------------------------
__global__ __launch_bounds__(256) void repack_kernel(
    const float* __restrict__ pre_w, const float* __restrict__ attn_w,
    const float* __restrict__ c3_w,
    __bf16* __restrict__ wA1, __bf16* __restrict__ wA2, float* __restrict__ wT3)
{
    int idx = blockIdx.x * 256 + threadIdx.x;
    if (idx < 64 * 576) {
        int o = idx / 576, rem = idx - o * 576, t = rem >> 6, c = rem & 63;
        wA1[idx] = (__bf16)pre_w[(o * 64 + c) * 9 + t];
    }
    if (idx < 16 * 576) {
        int e = idx / 576, rem = idx - e * 576, t = rem >> 6, c = rem & 63;
        wA2[idx] = (__bf16)attn_w[(e * 64 + c) * 9 + t];
    }
    if (idx < 64 * 64) {
        int f = idx >> 6, o = idx & 63;
        wT3[idx] = c3_w[o * 64 + f];
    }
}

// ---------------------------------------------------------------------------
// conv1 via MFMA 32x32x16 bf16: 9 taps x 4 c-chunks of K=16, accumulated.
// block = (2 rows, all 64 out ch); wave = M32 x N64 (one row, both halves).
// out written transposed bf16 -> xT1[b][y][x+1][o], borders zeroed.
// ---------------------------------------------------------------------------
__global__ __launch_bounds__(256) void conv1_mfma(
    const __bf16* __restrict__ xTs, const __bf16* __restrict__ wA1,
    const float* __restrict__ bias, __bf16* __restrict__ xT1)
{
    __shared__ __bf16 s_x[4 * XP * CP];
    const int b = blockIdx.y, y0 = blockIdx.x * 2;
    const int tid = threadIdx.x;

    for (int t = tid; t < 4 * XP * 8; t += 256) {
        int r = t / (XP * 8);
        int rem = t - r * (XP * 8);
        int x = rem >> 3, cg = rem & 7;
        int yy = y0 - 1 + r;
        bf16x8 v = {};
        if (yy >= 0 && yy < H)
            v = *(const bf16x8*)(xTs + (size_t)(b * H + yy) * YSTRIDE + x * F + cg * 8);
        *(bf16x8*)(s_x + (r * XP + x) * CP + cg * 8) = v;
    }
    __syncthreads();

    const int wave = tid >> 6, lane = tid & 63;
    const int mt = wave & 1;      // M-tile (o 0..31 / 32..63)
    const int np = wave >> 1;     // which of the 2 rows
    const int n = lane & 31, kh = lane >> 5;
    f32x16 acc0 = {}, acc1 = {};
    const __bf16* aBase = wA1 + (mt * 32 + n) * 576 + kh * 8;

    #pragma unroll
    for (int dy = 0; dy < 3; ++dy) {
        #pragma unroll
        for (int dx = 0; dx < 3; ++dx) {
            const int t9 = dy * 3 + dx;
            const __bf16* bBase = s_x + ((np + dy) * XP + (n + dx)) * CP + kh * 8;
            #pragma unroll
            for (int cq = 0; cq < 4; ++cq) {
                bf16x8 a  = *(const bf16x8*)(aBase + t9 * 64 + cq * 16);
                bf16x8 b0 = *(const bf16x8*)(bBase + cq * 16);
                bf16x8 b1 = *(const bf16x8*)(bBase + 32 * CP + cq * 16);
                acc0 = __builtin_amdgcn_mfma_f32_32x32x16_bf16(a, b0, acc0, 0, 0, 0);
                acc1 = __builtin_amdgcn_mfma_f32_32x32x16_bf16(a, b1, acc1, 0, 0, 0);
            }
        }
    }

    // epilogue: D row = (reg&3) + 8*(reg>>2) + 4*kh (+ mt*32), col = n
    __bf16* obase = xT1 + (size_t)(b * H + y0 + np) * YSTRIDE;
    #pragma unroll
    for (int g = 0; g < 4; ++g) {
        int o0 = mt * 32 + kh * 4 + g * 8;
        f32x4 b4 = *(const f32x4*)(bias + o0);
        bf16x4 v0, v1;
        #pragma unroll
        for (int r = 0; r < 4; ++r) {
            v0[r] = (__bf16)fmaxf(acc0[g * 4 + r] + b4[r], 0.f);
            v1[r] = (__bf16)fmaxf(acc1[g * 4 + r] + b4[r], 0.f);
        }
        *(bf16x4*)(obase + (n + 1) * F + o0) = v0;
        *(bf16x4*)(obase + (n + 33) * F + o0) = v1;
    }
    if (tid < 32) {  // zero x-borders of this block's 2 rows
        int r2 = tid >> 4, bd = (tid >> 3) & 1, cg = tid & 7;
        bf16x8 z = {};
        *(bf16x8*)(xT1 + (size_t)(b * H + y0 + r2) * YSTRIDE + (bd ? 65 : 0) * F + cg * 8) = z;
    }
}

// ---------------------------------------------------------------------------
// conv2 via MFMA 16x16x32 bf16: M=16(E), block = 4 rows, wave = one row (4 n-tiles).
// sigmoid epilogue -> attn (B,E,H,W) fp32.
// ---------------------------------------------------------------------------
__global__ __launch_bounds__(256) void conv2_mfma(
    const __bf16* __restrict__ xT1, const __bf16* __restrict__ wA2,
    const float* __restrict__ bias, float* __restrict__ attn)
{
    __shared__ __bf16 s_x[6 * XP * CP];
    const int b = blockIdx.y, y0 = blockIdx.x * 4;
    const int tid = threadIdx.x;

    for (int t = tid; t < 6 * XP * 8; t += 256) {
        int r = t / (XP * 8);
        int rem = t - r * (XP * 8);
        int x = rem >> 3, cg = rem & 7;
        int yy = y0 - 1 + r;
        bf16x8 v = {};
        if (yy >= 0 && yy < H)
            v = *(const bf16x8*)(xT1 + (size_t)(b * H + yy) * YSTRIDE + x * F + cg * 8);
        *(bf16x8*)(s_x + (r * XP + x) * CP + cg * 8) = v;
    }
    __syncthreads();

    const int w = tid >> 6, lane = tid & 63;
    const int n = lane & 15, quad = lane >> 4;
    f32x4 acc[4] = {};
    const __bf16* aBase = wA2 + n * 576 + quad * 8;   // A: m=lane&15, k=quad*8+j

    #pragma unroll
    for (int dy = 0; dy < 3; ++dy) {
        #pragma unroll
        for (int dx = 0; dx < 3; ++dx) {
            const int t9 = dy * 3 + dx;
            const __bf16* bBase = s_x + ((w + dy) * XP + (n + dx)) * CP + quad * 8;
            #pragma unroll
            for (int cq = 0; cq < 2; ++cq) {
                bf16x8 a = *(const bf16x8*)(aBase + t9 * 64 + cq * 32);
                #pragma unroll
                for (int i = 0; i < 4; ++i) {
                    bf16x8 bf = *(const bf16x8*)(bBase + (i * 16) * CP + cq * 32);
                    acc[i] = __builtin_amdgcn_mfma_f32_16x16x32_bf16(a, bf, acc[i], 0, 0, 0);
                }
            }
        }
    }

    const int y = y0 + w;
    #pragma unroll
    for (int i = 0; i < 4; ++i) {
        int x = i * 16 + n;
        #pragma unroll
        for (int r = 0; r < 4; ++r) {
            int e = quad * 4 + r;
            float val = acc[i][r] + bias[e];
            attn[((size_t)(b * E + e) * H + y) * W + x] = 1.f / (1.f + __expf(-val));
        }
    }
}

// ---------------------------------------------------------------------------
// sproj[b,o,y,x] = sum_f wT3[f][o] * state[b,f,y,x]   (fp32 vector)
// ---------------------------------------------------------------------------
__global__ __launch_bounds__(256) void sproj_kernel(
    const float* __restrict__ state, const float* __restrict__ wT3,
    float* __restrict__ out)
{
    const int b = blockIdx.y, y = blockIdx.x;
    const int tid = threadIdx.x;
    const int og = tid >> 4;
    const int x0 = (tid & 15) * 4;
    float acc[4][4] = {};
    const float* sp = state + (b * F * H + y) * W + x0;

    for (int f = 0; f < F; ++f) {
        float4 v4 = *(const float4*)(sp + f * HW);
        float4 wv = ((const float4*)(wT3 + f * 64))[og];
        float v[4] = {v4.x, v4.y, v4.z, v4.w};
        float wvv[4] = {wv.x, wv.y, wv.z, wv.w};
        #pragma unroll
        for (int i = 0; i < 4; ++i)
            #pragma unroll
            for (int j = 0; j < 4; ++j)
                acc[i][j] = fmaf(wvv[i], v[j], acc[i][j]);
    }
    #pragma unroll
    for (int i = 0; i < 4; ++i) {
        int o = og * 4 + i;
        #pragma unroll
        for (int j = 0; j < 4; ++j)
            out[((b * F + o) * H + y) * W + x0 + j] = acc[i][j];
    }
}

// ---------------------------------------------------------------------------
// reduce: out[b,e,o] += sum_p relu(attn[b,e,p]*sproj[b,o,p] + c3_b[o]) / 4356
// ---------------------------------------------------------------------------
__global__ __launch_bounds__(256) void reduce_kernel(
    const float* __restrict__ sproj, const float* __restrict__ attn,
    const float* __restrict__ c3_b, float* __restrict__ out)
{
    __shared__ __align__(16) float s_attn[64][16];   // [p][e]
    __shared__ __align__(16) float s_sp[64][64];     // [p][o]; reused for partials
    const int b = blockIdx.y;
    const int chunk = blockIdx.x;
    const int p0 = chunk * 64;
    const int tid = threadIdx.x;

    {
        int e = tid >> 4, pq = (tid & 15) * 4;
        float4 v = *(const float4*)(attn + (b * E + e) * HW + p0 + pq);
        s_attn[pq + 0][e] = v.x; s_attn[pq + 1][e] = v.y;
        s_attn[pq + 2][e] = v.z; s_attn[pq + 3][e] = v.w;
    }
    #pragma unroll
    for (int r = 0; r < 4; ++r) {
        int idx = r * 256 + tid;
        int o = idx >> 4, pq = (idx & 15) * 4;
        float4 v = *(const float4*)(sproj + (b * F + o) * HW + p0 + pq);
        s_sp[pq + 0][o] = v.x; s_sp[pq + 1][o] = v.y;
        s_sp[pq + 2][o] = v.z; s_sp[pq + 3][o] = v.w;
    }
    __syncthreads();

    const int combo = tid & 63;
    const int eg = combo >> 4;
    const int og = combo & 15;
    const int psub = tid >> 6;
    float4 cb4 = ((const float4*)c3_b)[og];
    float cb[4] = {cb4.x, cb4.y, cb4.z, cb4.w};

    float acc[4][4] = {};
    #pragma unroll 2
    for (int pp = 0; pp < 16; ++pp) {
        int p = psub * 16 + pp;
        float4 a4 = *(const float4*)&s_attn[p][eg * 4];
        float4 s4 = *(const float4*)&s_sp[p][og * 4];
        float a[4] = {a4.x, a4.y, a4.z, a4.w};
        float s[4] = {s4.x, s4.y, s4.z, s4.w};
        #pragma unroll
        for (int i = 0; i < 4; ++i)
            #pragma unroll
            for (int j = 0; j < 4; ++j)
                acc[i][j] += fmaxf(fmaf(a[i], s[j], cb[j]), 0.f);
    }

    __syncthreads();
    float* s_part = &s_sp[0][0];
    #pragma unroll
    for (int i = 0; i < 4; ++i)
        #pragma unroll
        for (int j = 0; j < 4; ++j)
            s_part[(psub * 64 + combo) * 16 + i * 4 + j] = acc[i][j];
    __syncthreads();

    {
        int cmb = tid >> 2, i = tid & 3;
        int e = (cmb >> 4) * 4 + i;
        #pragma unroll
        for (int j = 0; j < 4; ++j) {
            int o = (cmb & 15) * 4 + j;
            float v = 0.f;
            #pragma unroll
            for (int ps = 0; ps < 4; ++ps)
                v += s_part[(ps * 64 + cmb) * 16 + i * 4 + j];
            float add = v * (1.f / 4356.f);
            if (chunk == 0)
                add += 260.f * fmaxf(c3_b[o], 0.f) * (1.f / 4356.f);
            atomicAdd(&out[(b * E + e) * F + o], add);
        }
    }
}

// ---------------------------------------------------------------------------
extern "C" void kernel_launch(void* const* d_in, const int* in_sizes, int n_in,
                              void* d_out, int out_size, void* d_ws, size_t ws_size,
                              hipStream_t stream) {
    (void)in_sizes; (void)n_in; (void)out_size; (void)ws_size;
    const float* state  = (const float*)d_in[0];
    const float* pre_w  = (const float*)d_in[1];
    const float* pre_b  = (const float*)d_in[2];
    const float* attn_w = (const float*)d_in[3];
    const float* attn_b = (const float*)d_in[4];
    const float* c3_w   = (const float*)d_in[5];
    const float* c3_b   = (const float*)d_in[6];

    float* out      = (float*)d_out;
    float* attn_out = out + B * E * F;

    char* ws = (char*)d_ws;
    constexpr size_t XT_BYTES = (size_t)B * H * YSTRIDE * 2;   // 8,650,752
    __bf16* xTs   = (__bf16*)ws;
    __bf16* xT1   = (__bf16*)(ws + XT_BYTES);
    float*  sproj = (float*)ws;                  // overlays xTs/xT1 after conv2
    __bf16* wA1   = (__bf16*)(ws + 2 * XT_BYTES);
    __bf16* wA2   = (__bf16*)(ws + 2 * XT_BYTES + 73728);
    float*  wT3   = (float*)(ws + 2 * XT_BYTES + 73728 + 18432);

    hipMemsetAsync(out, 0, B * E * F * sizeof(float), stream);
    transpose_kernel<<<dim3(H, B), 256, 0, stream>>>(state, xTs);
    repack_kernel<<<144, 256, 0, stream>>>(pre_w, attn_w, c3_w, wA1, wA2, wT3);
    conv1_mfma<<<dim3(H / 2, B), 256, 0, stream>>>(xTs, wA1, pre_b, xT1);
    conv2_mfma<<<dim3(H / 4, B), 256, 0, stream>>>(xT1, wA2, attn_b, attn_out);
    sproj_kernel<<<dim3(H, B), 256, 0, stream>>>(state, wT3, sproj);
    reduce_kernel<<<dim3(64, B), 256, 0, stream>>>(sproj, attn_out, c3_b, out);
}

// Round 4
// 126.280 us; speedup vs baseline: 4.0547x; 1.1955x over previous
//
#include <hip/hip_runtime.h>
#include <math.h>

constexpr int B = 16, F = 64, E = 16, H = 64, W = 64;
constexpr int HW = H * W;
constexpr int XP = 66;          // padded x dim (1 zero col each side)
constexpr int CP = 72;          // LDS c-dim pad (2-way bank aliasing only)
constexpr int YSTRIDE = XP * F; // 4224 elems per (b,y) row in transposed bufs

typedef __bf16 bf16x8 __attribute__((ext_vector_type(8)));
typedef __bf16 bf16x4 __attribute__((ext_vector_type(4)));
typedef float f32x16 __attribute__((ext_vector_type(16)));
typedef float f32x4 __attribute__((ext_vector_type(4)));

// ---------------------------------------------------------------------------
// prep: blk<1024: transpose state -> xTs[b][y][x+1][c] bf16 (borders zeroed)
//       blk<1168: repack weights (wA1[o][t*64+c], wA2[e][t*64+c], wT3b=bf16(c3_w))
//       else    : zero d_out[0..16383] (the (B,E,F) accumulator region)
// ---------------------------------------------------------------------------
__global__ __launch_bounds__(256) void prep_kernel(
    const float* __restrict__ state, const float* __restrict__ pre_w,
    const float* __restrict__ attn_w, const float* __restrict__ c3_w,
    __bf16* __restrict__ xTs, __bf16* __restrict__ wA1,
    __bf16* __restrict__ wA2, __bf16* __restrict__ wT3b,
    float* __restrict__ out0)
{
    __shared__ float s_t[64][68];
    const int blk = blockIdx.x;
    const int tid = threadIdx.x;

    if (blk < 1024) {
        const int b = blk >> 6, y = blk & 63;
        {
            int c = tid >> 2, x0 = (tid & 3) * 16;
            const float* src = state + ((size_t)(b * F + c) * H + y) * W + x0;
            #pragma unroll
            for (int q = 0; q < 4; ++q)
                *(float4*)&s_t[c][x0 + 4 * q] = *(const float4*)(src + 4 * q);
        }
        __syncthreads();
        __bf16* dst = xTs + (size_t)(b * H + y) * YSTRIDE;
        #pragma unroll
        for (int i = 0; i < 2; ++i) {
            int t = tid + i * 256;
            int x = t >> 3, cg = t & 7;
            bf16x8 v;
            #pragma unroll
            for (int j = 0; j < 8; ++j) v[j] = (__bf16)s_t[cg * 8 + j][x];
            *(bf16x8*)(dst + (x + 1) * F + cg * 8) = v;
        }
        if (tid < 16) {
            int bd = tid >> 3, cg = tid & 7;
            bf16x8 z = {};
            *(bf16x8*)(dst + (bd ? 65 : 0) * F + cg * 8) = z;
        }
    } else if (blk < 1168) {
        int idx = (blk - 1024) * 256 + tid;
        if (idx < 64 * 576) {
            int o = idx / 576, rem = idx - o * 576, t = rem >> 6, c = rem & 63;
            wA1[idx] = (__bf16)pre_w[(o * 64 + c) * 9 + t];
        }
        if (idx < 16 * 576) {
            int e = idx / 576, rem = idx - e * 576, t = rem >> 6, c = rem & 63;
            wA2[idx] = (__bf16)attn_w[(e * 64 + c) * 9 + t];
        }
        if (idx < 64 * 64) {
            wT3b[idx] = (__bf16)c3_w[idx];   // already [o][f] row-major
        }
    } else {
        int idx = (blk - 1168) * 256 + tid;  // 16 blocks cover 16384 floats
        float4 z = {0.f, 0.f, 0.f, 0.f};
        *(float4*)(out0 + idx * 4) = z;
    }
}

// ---------------------------------------------------------------------------
// conv1 via MFMA 32x32x16 bf16: 9 taps x 4 c-chunks of K=16, accumulated.
// block = (2 rows, all 64 out ch); wave = M32 x N64 (one row, both halves).
// out written transposed bf16 -> xT1[b][y][x+1][o], borders zeroed.
// ---------------------------------------------------------------------------
__global__ __launch_bounds__(256) void conv1_mfma(
    const __bf16* __restrict__ xTs, const __bf16* __restrict__ wA1,
    const float* __restrict__ bias, __bf16* __restrict__ xT1)
{
    __shared__ __bf16 s_x[4 * XP * CP];
    const int b = blockIdx.y, y0 = blockIdx.x * 2;
    const int tid = threadIdx.x;

    for (int t = tid; t < 4 * XP * 8; t += 256) {
        int r = t / (XP * 8);
        int rem = t - r * (XP * 8);
        int x = rem >> 3, cg = rem & 7;
        int yy = y0 - 1 + r;
        bf16x8 v = {};
        if (yy >= 0 && yy < H)
            v = *(const bf16x8*)(xTs + (size_t)(b * H + yy) * YSTRIDE + x * F + cg * 8);
        *(bf16x8*)(s_x + (r * XP + x) * CP + cg * 8) = v;
    }
    __syncthreads();

    const int wave = tid >> 6, lane = tid & 63;
    const int mt = wave & 1;      // M-tile (o 0..31 / 32..63)
    const int np = wave >> 1;     // which of the 2 rows
    const int n = lane & 31, kh = lane >> 5;
    f32x16 acc0 = {}, acc1 = {};
    const __bf16* aBase = wA1 + (mt * 32 + n) * 576 + kh * 8;

    #pragma unroll
    for (int dy = 0; dy < 3; ++dy) {
        #pragma unroll
        for (int dx = 0; dx < 3; ++dx) {
            const int t9 = dy * 3 + dx;
            const __bf16* bBase = s_x + ((np + dy) * XP + (n + dx)) * CP + kh * 8;
            #pragma unroll
            for (int cq = 0; cq < 4; ++cq) {
                bf16x8 a  = *(const bf16x8*)(aBase + t9 * 64 + cq * 16);
                bf16x8 b0 = *(const bf16x8*)(bBase + cq * 16);
                bf16x8 b1 = *(const bf16x8*)(bBase + 32 * CP + cq * 16);
                acc0 = __builtin_amdgcn_mfma_f32_32x32x16_bf16(a, b0, acc0, 0, 0, 0);
                acc1 = __builtin_amdgcn_mfma_f32_32x32x16_bf16(a, b1, acc1, 0, 0, 0);
            }
        }
    }

    // epilogue: D row = (reg&3) + 8*(reg>>2) + 4*kh (+ mt*32), col = n
    __bf16* obase = xT1 + (size_t)(b * H + y0 + np) * YSTRIDE;
    #pragma unroll
    for (int g = 0; g < 4; ++g) {
        int o0 = mt * 32 + kh * 4 + g * 8;
        f32x4 b4 = *(const f32x4*)(bias + o0);
        bf16x4 v0, v1;
        #pragma unroll
        for (int r = 0; r < 4; ++r) {
            v0[r] = (__bf16)fmaxf(acc0[g * 4 + r] + b4[r], 0.f);
            v1[r] = (__bf16)fmaxf(acc1[g * 4 + r] + b4[r], 0.f);
        }
        *(bf16x4*)(obase + (n + 1) * F + o0) = v0;
        *(bf16x4*)(obase + (n + 33) * F + o0) = v1;
    }
    if (tid < 32) {  // zero x-borders of this block's 2 rows
        int r2 = tid >> 4, bd = (tid >> 3) & 1, cg = tid & 7;
        bf16x8 z = {};
        *(bf16x8*)(xT1 + (size_t)(b * H + y0 + r2) * YSTRIDE + (bd ? 65 : 0) * F + cg * 8) = z;
    }
}

// ---------------------------------------------------------------------------
// conv2 via MFMA 16x16x32 bf16: M=16(E), block = 4 rows, wave = one row.
// sigmoid epilogue -> attn (B,E,H,W) fp32.
// ---------------------------------------------------------------------------
__global__ __launch_bounds__(256) void conv2_mfma(
    const __bf16* __restrict__ xT1, const __bf16* __restrict__ wA2,
    const float* __restrict__ bias, float* __restrict__ attn)
{
    __shared__ __bf16 s_x[6 * XP * CP];
    const int b = blockIdx.y, y0 = blockIdx.x * 4;
    const int tid = threadIdx.x;

    for (int t = tid; t < 6 * XP * 8; t += 256) {
        int r = t / (XP * 8);
        int rem = t - r * (XP * 8);
        int x = rem >> 3, cg = rem & 7;
        int yy = y0 - 1 + r;
        bf16x8 v = {};
        if (yy >= 0 && yy < H)
            v = *(const bf16x8*)(xT1 + (size_t)(b * H + yy) * YSTRIDE + x * F + cg * 8);
        *(bf16x8*)(s_x + (r * XP + x) * CP + cg * 8) = v;
    }
    __syncthreads();

    const int w = tid >> 6, lane = tid & 63;
    const int n = lane & 15, quad = lane >> 4;
    f32x4 acc[4] = {};
    const __bf16* aBase = wA2 + n * 576 + quad * 8;   // A: m=lane&15, k=quad*8+j

    #pragma unroll
    for (int dy = 0; dy < 3; ++dy) {
        #pragma unroll
        for (int dx = 0; dx < 3; ++dx) {
            const int t9 = dy * 3 + dx;
            const __bf16* bBase = s_x + ((w + dy) * XP + (n + dx)) * CP + quad * 8;
            #pragma unroll
            for (int cq = 0; cq < 2; ++cq) {
                bf16x8 a = *(const bf16x8*)(aBase + t9 * 64 + cq * 32);
                #pragma unroll
                for (int i = 0; i < 4; ++i) {
                    bf16x8 bf = *(const bf16x8*)(bBase + (i * 16) * CP + cq * 32);
                    acc[i] = __builtin_amdgcn_mfma_f32_16x16x32_bf16(a, bf, acc[i], 0, 0, 0);
                }
            }
        }
    }

    const int y = y0 + w;
    #pragma unroll
    for (int i = 0; i < 4; ++i) {
        int x = i * 16 + n;
        #pragma unroll
        for (int r = 0; r < 4; ++r) {
            int e = quad * 4 + r;
            float val = acc[i][r] + bias[e];
            attn[((size_t)(b * E + e) * H + y) * W + x] = 1.f / (1.f + __expf(-val));
        }
    }
}

// ---------------------------------------------------------------------------
// reduce (sproj fused via MFMA):
//   sproj[o][p] = sum_f c3_w[o][f]*state[f][p]  -- 4 MFMAs/wave from xTs+wT3b
//   out[b,e,o] += sum_p relu(attn[b,e,p]*sproj[o][p] + c3_b[o]) / 4356
// block = (b, one row y = 64 pixels).
// ---------------------------------------------------------------------------
__global__ __launch_bounds__(256) void reduce_fused(
    const __bf16* __restrict__ xTs, const __bf16* __restrict__ wT3b,
    const float* __restrict__ attn, const float* __restrict__ c3_b,
    float* __restrict__ out)
{
    __shared__ __align__(16) float s_attn[64][16];   // [p][e]
    __shared__ __align__(16) float s_sp[64][68];     // [p][o]; reused for partials
    const int b = blockIdx.y, y = blockIdx.x;
    const int tid = threadIdx.x;

    // stage attn: 16e x 64p -> [p][e]
    {
        int e = tid >> 4, pq = (tid & 15) * 4;
        float4 v = *(const float4*)(attn + ((size_t)(b * E + e) * H + y) * W + pq);
        s_attn[pq + 0][e] = v.x; s_attn[pq + 1][e] = v.y;
        s_attn[pq + 2][e] = v.z; s_attn[pq + 3][e] = v.w;
    }

    // sproj via MFMA 32x32x16: wave = (mt: o-tile, nt: p-tile), K=64 in 4 chunks
    {
        const int wave = tid >> 6, lane = tid & 63;
        const int mt = wave & 1, nt = wave >> 1;
        const int n = lane & 31, kh = lane >> 5;
        const __bf16* bBase = xTs + (size_t)(b * H + y) * YSTRIDE + (nt * 32 + n + 1) * F + kh * 8;
        const __bf16* aBase = wT3b + (mt * 32 + n) * 64 + kh * 8;
        f32x16 acc = {};
        #pragma unroll
        for (int cq = 0; cq < 4; ++cq) {
            bf16x8 a  = *(const bf16x8*)(aBase + cq * 16);
            bf16x8 bb = *(const bf16x8*)(bBase + cq * 16);
            acc = __builtin_amdgcn_mfma_f32_32x32x16_bf16(a, bb, acc, 0, 0, 0);
        }
        #pragma unroll
        for (int g = 0; g < 4; ++g)
            #pragma unroll
            for (int r = 0; r < 4; ++r)
                s_sp[nt * 32 + n][mt * 32 + kh * 4 + g * 8 + r] = acc[g * 4 + r];
    }
    __syncthreads();

    const int combo = tid & 63;
    const int eg = combo >> 4;       // 0..3  (4 e's)
    const int og = combo & 15;       // 0..15 (4 o's)
    const int psub = tid >> 6;       // 0..3  (16 pixels each)
    float4 cb4 = ((const float4*)c3_b)[og];
    float cb[4] = {cb4.x, cb4.y, cb4.z, cb4.w};

    float acc[4][4] = {};
    #pragma unroll 2
    for (int pp = 0; pp < 16; ++pp) {
        int p = psub * 16 + pp;
        float4 a4 = *(const float4*)&s_attn[p][eg * 4];
        float4 s4 = *(const float4*)&s_sp[p][og * 4];
        float a[4] = {a4.x, a4.y, a4.z, a4.w};
        float s[4] = {s4.x, s4.y, s4.z, s4.w};
        #pragma unroll
        for (int i = 0; i < 4; ++i)
            #pragma unroll
            for (int j = 0; j < 4; ++j)
                acc[i][j] += fmaxf(fmaf(a[i], s[j], cb[j]), 0.f);
    }

    __syncthreads();
    float* s_part = &s_sp[0][0];     // 4096 of 4352 floats
    #pragma unroll
    for (int i = 0; i < 4; ++i)
        #pragma unroll
        for (int j = 0; j < 4; ++j)
            s_part[(psub * 64 + combo) * 16 + i * 4 + j] = acc[i][j];
    __syncthreads();

    {
        int cmb = tid >> 2, i = tid & 3;
        int e = (cmb >> 4) * 4 + i;
        #pragma unroll
        for (int j = 0; j < 4; ++j) {
            int o = (cmb & 15) * 4 + j;
            float v = 0.f;
            #pragma unroll
            for (int ps = 0; ps < 4; ++ps)
                v += s_part[(ps * 64 + cmb) * 16 + i * 4 + j];
            float add = v * (1.f / 4356.f);
            if (y == 0)
                add += 260.f * fmaxf(c3_b[o], 0.f) * (1.f / 4356.f);
            atomicAdd(&out[(b * E + e) * F + o], add);
        }
    }
}

// ---------------------------------------------------------------------------
extern "C" void kernel_launch(void* const* d_in, const int* in_sizes, int n_in,
                              void* d_out, int out_size, void* d_ws, size_t ws_size,
                              hipStream_t stream) {
    (void)in_sizes; (void)n_in; (void)out_size; (void)ws_size;
    const float* state  = (const float*)d_in[0];
    const float* pre_w  = (const float*)d_in[1];
    const float* pre_b  = (const float*)d_in[2];
    const float* attn_w = (const float*)d_in[3];
    const float* attn_b = (const float*)d_in[4];
    const float* c3_w   = (const float*)d_in[5];
    const float* c3_b   = (const float*)d_in[6];

    float* out      = (float*)d_out;
    float* attn_out = out + B * E * F;

    char* ws = (char*)d_ws;
    constexpr size_t XT_BYTES = (size_t)B * H * YSTRIDE * 2;   // 8,650,752
    __bf16* xTs  = (__bf16*)ws;
    __bf16* xT1  = (__bf16*)(ws + XT_BYTES);
    __bf16* wA1  = (__bf16*)(ws + 2 * XT_BYTES);
    __bf16* wA2  = (__bf16*)(ws + 2 * XT_BYTES + 73728);
    __bf16* wT3b = (__bf16*)(ws + 2 * XT_BYTES + 73728 + 18432);

    prep_kernel<<<1184, 256, 0, stream>>>(state, pre_w, attn_w, c3_w,
                                          xTs, wA1, wA2, wT3b, out);
    conv1_mfma<<<dim3(H / 2, B), 256, 0, stream>>>(xTs, wA1, pre_b, xT1);
    conv2_mfma<<<dim3(H / 4, B), 256, 0, stream>>>(xT1, wA2, attn_b, attn_out);
    reduce_fused<<<dim3(H, B), 256, 0, stream>>>(xTs, wT3b, attn_out, c3_b, out);
}